// Round 2
// baseline (414394.092 us; speedup 1.0000x reference)
//
#include <hip/hip_runtime.h>
#include <stdint.h>

// RNN-T greedy decode v4 — 3-round fence-free pipeline, f64-native dots, 2 blocks/CU.
//
// v3 post-mortem: fence-free protocol good (FETCH dropped), but 1 wave/SIMD
// (latency-bound) and 12 cyc/MAC from per-MAC f32->f64 converts made it 344ms.
// v4: f64 weights precomputed (1 v_fma_f64 per MAC), h/tanh staged to LDS as
// f64 once per round, 512 blocks (2/CU, 8 rows per block, 32 threads/row),
// XCD-pinned weight slices (~2.7MB/XCD L2 working set), shfl-based argmax.

typedef unsigned int u32;
typedef unsigned long long u64;

constexpr int NGB = 256;          // gate+pred blocks (64 unit-groups x 4 row-groups)
constexpr int NOB = 256;          // out blocks       (64 col-groups  x 4 row-groups)
constexpr int NBLK = NGB + NOB;   // 512 = 2 per CU
constexpr int HSTR = 646;         // LDS doubles per row (row bank offset 12, 16B aligned)

// ---- static device scratch ----
__device__ float  g_encT[1000 * 32 * 640];  // enc@Wenc + b_joint, [T][B][J]
__device__ float  g_lut[1025 * 2560];       // embed@Wx + b_lstm (row 1024 = b_lstm)
__device__ double g_WhT64[2560 * 640];      // Wh^T   [4H][H] as f64
__device__ double g_WpT64[640 * 640];       // Wpred^T[J][H]  as f64
__device__ double g_WoT64[1025 * 640];      // Wout^T [V+1][J] as f64
__device__ float  g_hnew[2 * 32 * 640];     // h_new, double-buffered by parity
__device__ float  g_tnh[32 * 640];          // tanh(joint pre-act)
__device__ u64    g_cval[32 * 64];          // per-(row, col-group) best (f64 bits)
__device__ int    g_cidx[32 * 64];
__device__ u32    g_cnt[64 * 32];           // counters, 128 B apart

constexpr int F1L = 0,  F1R = 16;  // 16 leaves x 16 gate blocks
constexpr int F2L = 17, F2R = 33;  // 16 leaves x 16 gate blocks
constexpr int F3L = 34, F3R = 50;  // 16 leaves x 16 out blocks

__device__ __forceinline__ float sigmf(float x) { return 1.0f / (1.0f + expf(-x)); }

// caller: thread 0, after __syncthreads() (vmcnt-drain => data stores at MALL).
__device__ __forceinline__ void bump(int leaf, int root, int step) {
  u32 old = __hip_atomic_fetch_add(&g_cnt[leaf * 32], 1u, __ATOMIC_RELAXED, __HIP_MEMORY_SCOPE_AGENT);
  if (old + 1u == (u32)(step + 1) * 16u)
    __hip_atomic_fetch_add(&g_cnt[root * 32], 1u, __ATOMIC_RELAXED, __HIP_MEMORY_SCOPE_AGENT);
}

__device__ __forceinline__ void waitc(int root, u32 target) {
  if (threadIdx.x == 0) {
    while (__hip_atomic_load(&g_cnt[root * 32], __ATOMIC_RELAXED, __HIP_MEMORY_SCOPE_AGENT) < target)
      __builtin_amdgcn_s_sleep(1);
  }
  __syncthreads();
}

// f64 dot, n % 4 == 0. (double)f32 products are exact; fma == mul+add here.
__device__ __forceinline__ double dotd(const double* __restrict__ h,
                                       const double* __restrict__ w, int n) {
  double a0 = 0.0, a1 = 0.0;
#pragma unroll 4
  for (int k = 0; k < n; k += 4) {
    double2 x0 = *(const double2*)(h + k);
    double2 w0 = *(const double2*)(w + k);
    double2 x1 = *(const double2*)(h + k + 2);
    double2 w1 = *(const double2*)(w + k + 2);
    a0 = fma(x0.x, w0.x, a0); a0 = fma(x0.y, w0.y, a0);
    a1 = fma(x1.x, w1.x, a1); a1 = fma(x1.y, w1.y, a1);
  }
  return a0 + a1;
}

// stage 8 rows x 640 f32 (MALL-coherent u64 loads) -> LDS f64 [8][HSTR]
__device__ __forceinline__ void stage8(const float* gsrc, double* dst, int tid) {
  const u64* src = (const u64*)gsrc;
#pragma unroll
  for (int i = 0; i < 10; i++) {
    int idx = tid + i * 256;  // < 2560
    u64 v = __hip_atomic_load((u64*)(src + idx), __ATOMIC_RELAXED, __HIP_MEMORY_SCOPE_AGENT);
    int p2 = idx * 2;
    int r = p2 / 640, k = p2 - r * 640;
    double2 d;
    d.x = (double)__uint_as_float((u32)v);
    d.y = (double)__uint_as_float((u32)(v >> 32));
    *(double2*)&dst[r * HSTR + k] = d;
  }
}

// ---------------- precompute: LUT = embed @ Wx + b_lstm (row 1024 = b_lstm) ----------
__global__ __launch_bounds__(256) void k_lut(const float* __restrict__ embed,
                                             const float* __restrict__ Wx,
                                             const float* __restrict__ b_lstm) {
  const int tid = threadIdx.x;
  const int cg = blockIdx.x % 10, rg = blockIdx.x / 10;  // rg 0..128
  const int c = cg * 256 + tid;
  const int r0 = rg * 8;
  double acc[8];
  double bl = (double)b_lstm[c];
#pragma unroll
  for (int i = 0; i < 8; i++) acc[i] = bl;
  for (int e = 0; e < 640; e++) {
    double wx = (double)Wx[(size_t)e * 2560 + c];
#pragma unroll
    for (int i = 0; i < 8; i++) {
      int r = r0 + i;
      if (r < 1024) acc[i] += (double)embed[(size_t)r * 640 + e] * wx;
    }
  }
#pragma unroll
  for (int i = 0; i < 8; i++) {
    int r = r0 + i;
    if (r < 1025) g_lut[(size_t)r * 2560 + c] = (float)acc[i];
  }
  if (blockIdx.x == 0) {  // re-init counters every call (graph replay)
    for (int i = tid; i < 64 * 32; i += 256) g_cnt[i] = 0u;
  }
}

// ------------- precompute: encT[t][b][j] = sum_d enc[b][d][t]*Wenc[d][j] + b_joint[j] --
__global__ __launch_bounds__(256) void k_encproj(const float* __restrict__ enc,
                                                 const float* __restrict__ Wenc,
                                                 const float* __restrict__ bj) {
  __shared__ __align__(16) float As[16][68];
  __shared__ __align__(16) float Bs[16][68];
  const int tid = threadIdx.x;
  const int jt = blockIdx.x % 10, tt = blockIdx.x / 10;  // 10 j-tiles, 16 t-tiles
  const int b = blockIdx.y;
  const int t0 = tt * 64, j0 = jt * 64;
  const int ty = tid >> 4, tx = tid & 15;
  double acc[4][4] = {};
  const float* Ab = enc + (size_t)b * 640 * 1000;
  for (int d0 = 0; d0 < 640; d0 += 16) {
#pragma unroll
    for (int i = 0; i < 4; i++) {
      int idx = tid + i * 256;
      int d = idx >> 6, t = idx & 63;
      As[d][t] = (t0 + t < 1000) ? Ab[(size_t)(d0 + d) * 1000 + t0 + t] : 0.f;
      Bs[d][t] = Wenc[(size_t)(d0 + d) * 640 + j0 + t];
    }
    __syncthreads();
#pragma unroll
    for (int kk = 0; kk < 16; kk++) {
      float4 av = *(const float4*)&As[kk][ty * 4];
      float4 bv = *(const float4*)&Bs[kk][tx * 4];
      float a[4] = {av.x, av.y, av.z, av.w};
      float bb[4] = {bv.x, bv.y, bv.z, bv.w};
#pragma unroll
      for (int i = 0; i < 4; i++)
#pragma unroll
        for (int j = 0; j < 4; j++) acc[i][j] += (double)a[i] * (double)bb[j];
    }
    __syncthreads();
  }
#pragma unroll
  for (int i = 0; i < 4; i++) {
    int t = t0 + ty * 4 + i;
    if (t < 1000)
#pragma unroll
      for (int j = 0; j < 4; j++)
        g_encT[(size_t)t * 20480 + b * 640 + j0 + tx * 4 + j] =
            (float)(acc[i][j] + (double)bj[j0 + tx * 4 + j]);
  }
}

// ------------- precompute: transposed f64 weights ------------------------------------
__global__ __launch_bounds__(256) void k_tr(const float* __restrict__ Wh,
                                            const float* __restrict__ Wpred,
                                            const float* __restrict__ Wout) {
  const int bid = blockIdx.x, tid = threadIdx.x;
  if (bid < 2560) {
    for (int k = tid; k < 640; k += 256)
      g_WhT64[(size_t)bid * 640 + k] = (double)Wh[(size_t)k * 2560 + bid];
  } else if (bid < 3200) {
    int c = bid - 2560;
    for (int k = tid; k < 640; k += 256)
      g_WpT64[(size_t)c * 640 + k] = (double)Wpred[(size_t)k * 640 + c];
  } else {
    int c = bid - 3200;  // < 1025
    for (int k = tid; k < 640; k += 256)
      g_WoT64[(size_t)c * 640 + k] = (double)Wout[(size_t)k * 1025 + c];
  }
}

// ------------------------------- persistent decode ------------------------------------
__global__ __launch_bounds__(256, 2) void k_decode(float* __restrict__ out,
                                                   const int* __restrict__ lens,
                                                   const float* __restrict__ b_out) {
  __shared__ __align__(16) double hst[8 * HSTR];  // staged h / tanh (f64), 8 rows
  __shared__ __align__(16) float  exA[320];       // [8][20][2] gate pre-acts (f32)
  __shared__ __align__(16) double ex2[160];       // [8][10][2] pred halves
  __shared__ __align__(16) double exB[1280];      // [8][40][4] G_spec quarters

  const int tid = threadIdx.x;
  const int bid = blockIdx.x;
  const int bloc = tid >> 5;        // local row 0..7 (32 threads per row)
  const int c = tid & 31;

  if (bid < NGB) {
    // ========== GATE+PRED role: 10 units x 8 rows; XCD-pinned unit slice ==========
    const int xcd = bid & 7, slot = bid >> 3;
    const int ug = xcd * 8 + (slot & 7);   // 0..63
    const int rg = slot >> 3;              // 0..3
    const int u0 = ug * 10;
    const int b = rg * 8 + bloc;
    const int len_r = lens[b];
    // pair-task c<20: pt=0 -> (i,g) of unit ul; pt=1 -> (f,o) of unit ul
    const int pt = c / 10, ul = c % 10;
    const int cA0 = (pt ? 640 : 0) + u0 + ul;      // i or f col of Wh-gate space
    const int cA1 = (pt ? 1920 : 1280) + u0 + ul;  // g or o col
    const int lcA0 = c, lcA1 = 20 + c;             // exB local col ids [i,f,g,o]

    double GA0 = 0.0, GA1 = 0.0, ccur = 0.0;
    float hcur = 0.0f;
    int last_r = 1024;
    int alive = (0 < len_r) ? 1 : 0;
    int ti = 0, si = 0;

    for (int step = 0; step < 5000; step++) {
      // ---- phase A: gates = G + LUT[last]; pointwise -> h_new; publish ----
      float encf = 0.0f;
      if (c < 10) encf = g_encT[(size_t)ti * 20480 + b * 640 + u0 + c];
      const float* lrow = g_lut + (size_t)last_r * 2560;
      if (c < 20) {
        exA[(bloc * 20 + c) * 2 + 0] = (float)(GA0 + (double)lrow[cA0]);
        exA[(bloc * 20 + c) * 2 + 1] = (float)(GA1 + (double)lrow[cA1]);
      }
      __syncthreads();
      double cn = 0.0; float hn = 0.0f;
      if (c < 10) {
        float fi = exA[(bloc * 20 + c) * 2 + 0];
        float fg = exA[(bloc * 20 + c) * 2 + 1];
        float ff = exA[(bloc * 20 + c + 10) * 2 + 0];
        float fo = exA[(bloc * 20 + c + 10) * 2 + 1];
        cn = (double)sigmf(ff) * ccur + (double)sigmf(fi) * (double)tanhf(fg);
        hn = sigmf(fo) * tanhf((float)cn);
        __hip_atomic_store(&g_hnew[(step & 1) * 20480 + b * 640 + u0 + c], hn,
                           __ATOMIC_RELAXED, __HIP_MEMORY_SCOPE_AGENT);
      }
      __syncthreads();  // vmcnt-drain: h stores at MALL before bump
      if (tid == 0) bump(F1L + (bid >> 4), F1R, step);
      waitc(F1R, (u32)(step + 1) * 16u);

      // ---- stage full h (f64) for our 8 rows ----
      stage8(g_hnew + (step & 1) * 20480 + rg * 5120, hst, tid);
      __syncthreads();

      // ---- pred: tanh(encT + h @ Wpred) for our 10 j-cols ----
      if (c < 20) {
        double a = dotd(&hst[bloc * HSTR + pt * 320],
                        g_WpT64 + (size_t)(u0 + ul) * 640 + pt * 320, 320);
        ex2[(bloc * 10 + ul) * 2 + pt] = a;
      }
      __syncthreads();
      if (c < 10) {
        double tot = ex2[(bloc * 10 + c) * 2 + 0] + ex2[(bloc * 10 + c) * 2 + 1];
        float th = tanhf((float)((double)encf + tot));
        __hip_atomic_store(&g_tnh[b * 640 + u0 + c], th,
                           __ATOMIC_RELAXED, __HIP_MEMORY_SCOPE_AGENT);
      }
      __syncthreads();
      if (tid == 0) bump(F2L + (bid >> 4), F2R, step);

      // ---- phase B: speculative G_spec = h_new @ Wh (overlaps out round) ----
#pragma unroll
      for (int s = 0; s < 5; s++) {
        int tt = c + 32 * s;                 // 0..159
        int lc = tt % 40, q = tt / 40;       // local col, k-quarter
        int gb = lc / 10;                    // 0:i 1:f 2:g 3:o
        int col = ((gb == 0) ? 0 : (gb == 1) ? 640 : (gb == 2) ? 1280 : 1920) + u0 + lc % 10;
        double a = dotd(&hst[bloc * HSTR + q * 160],
                        g_WhT64 + (size_t)col * 640 + q * 160, 160);
        exB[(bloc * 40 + lc) * 4 + q] = a;
      }
      waitc(F3R, (u32)(step + 1) * 16u);

      // ---- commit: gather G_spec, per-row argmax over 64 candidates (shfl) ----
      double nGA0 = 0.0, nGA1 = 0.0;
      if (c < 20) {
        nGA0 = exB[(bloc * 40 + lcA0) * 4 + 0] + exB[(bloc * 40 + lcA0) * 4 + 1]
             + exB[(bloc * 40 + lcA0) * 4 + 2] + exB[(bloc * 40 + lcA0) * 4 + 3];
        nGA1 = exB[(bloc * 40 + lcA1) * 4 + 0] + exB[(bloc * 40 + lcA1) * 4 + 1]
             + exB[(bloc * 40 + lcA1) * 4 + 2] + exB[(bloc * 40 + lcA1) * 4 + 3];
      }
      u64 v1b = __hip_atomic_load(&g_cval[b * 64 + c], __ATOMIC_RELAXED, __HIP_MEMORY_SCOPE_AGENT);
      int  i1  = __hip_atomic_load(&g_cidx[b * 64 + c], __ATOMIC_RELAXED, __HIP_MEMORY_SCOPE_AGENT);
      u64 v2b = __hip_atomic_load(&g_cval[b * 64 + c + 32], __ATOMIC_RELAXED, __HIP_MEMORY_SCOPE_AGENT);
      int  i2  = __hip_atomic_load(&g_cidx[b * 64 + c + 32], __ATOMIC_RELAXED, __HIP_MEMORY_SCOPE_AGENT);
      double bv = __longlong_as_double((long long)v1b); int bi = i1;
      double v2 = __longlong_as_double((long long)v2b);
      if (v2 > bv || (v2 == bv && i2 < bi)) { bv = v2; bi = i2; }
#pragma unroll
      for (int m = 1; m < 32; m <<= 1) {   // reduce within the 32-lane row group
        double vv = __shfl_xor(bv, m, 64);
        int ii = __shfl_xor(bi, m, 64);
        if (vv > bv || (vv == bv && ii < bi)) { bv = vv; bi = ii; }
      }
      int sym = bi;
      int em = (alive && sym != 1024) ? 1 : 0;
      if (ug == 0 && c == 0)
        out[(size_t)b * 5000 + step] = (float)(em ? sym : 1024);
      if (em) {
        last_r = sym;
        if (c < 20) { GA0 = nGA0; GA1 = nGA1; }
        if (c < 10) { ccur = cn; hcur = hn; }
      }
      alive = (si == 4) ? ((ti + 1 < len_r) ? 1 : 0) : em;
      si++; if (si == 5) { si = 0; ti++; }
      __syncthreads();  // exA/exB WAR across iterations
    }
    if (c < 10) {  // cache_rnn_state = stack([h, c])
      out[160000 + b * 640 + u0 + c] = hcur;
      out[160000 + 20480 + b * 640 + u0 + c] = (float)ccur;
    }

  } else {
    // ========== OUT role: 16 Wout cols x 8 rows; XCD-pinned col slice ==========
    const int o = bid - NGB;
    const int xcd = o & 7, slot = o >> 3;
    const int cg = xcd * 8 + (slot & 7);   // 0..63
    const int rg = slot >> 3;              // 0..3
    const int b = rg * 8 + bloc;
    const int col = cg * 16 + (c & 15);    // <= 1023
    const int half = c >> 4;
    const double* wrow = g_WoT64 + (size_t)col * 640 + half * 320;
    const double bo = (double)b_out[col];
    const bool blkrole = (cg == 63);       // also owns blank col 1024
    const double bo1024 = (double)b_out[1024];
    const double* wbl = g_WoT64 + (size_t)1024 * 640;

    for (int step = 0; step < 5000; step++) {
      waitc(F2R, (u32)(step + 1) * 16u);
      stage8(g_tnh + rg * 5120, hst, tid);
      __syncthreads();
      double a = dotd(&hst[bloc * HSTR + half * 320], wrow, 320);
      a += __shfl_xor(a, 16, 64);          // join the two k-halves of this col
      double bv = a + bo; int bi = col;
#pragma unroll
      for (int m = 1; m < 16; m <<= 1) {   // argmax over 16 cols (lanes 0..15 dup'd)
        double vv = __shfl_xor(bv, m, 64);
        int ii = __shfl_xor(bi, m, 64);
        if (vv > bv || (vv == bv && ii < bi)) { bv = vv; bi = ii; }
      }
      if (blkrole) {                       // blank logit: 32 lanes x 20 k
        double ab = dotd(&hst[bloc * HSTR + c * 20], wbl + c * 20, 20);
#pragma unroll
        for (int m = 1; m < 32; m <<= 1) ab += __shfl_xor(ab, m, 64);
        if (c == 0) {
          double blv = ab + bo1024;
          if (blv > bv) { bv = blv; bi = 1024; }  // blank loses ties (idx 1024 max)
        }
      }
      if (c == 0) {
        __hip_atomic_store(&g_cval[b * 64 + cg], (u64)__double_as_longlong(bv),
                           __ATOMIC_RELAXED, __HIP_MEMORY_SCOPE_AGENT);
        __hip_atomic_store(&g_cidx[b * 64 + cg], bi,
                           __ATOMIC_RELAXED, __HIP_MEMORY_SCOPE_AGENT);
      }
      __syncthreads();  // vmcnt-drain before bump
      if (tid == 0) bump(F3L + (o >> 4), F3R, step);
    }
  }
}

extern "C" void kernel_launch(void* const* d_in, const int* in_sizes, int n_in,
                              void* d_out, int out_size, void* d_ws, size_t ws_size,
                              hipStream_t stream) {
  const float* enc = (const float*)d_in[0];
  const int* lens = (const int*)d_in[1];
  const float* embed = (const float*)d_in[2];
  const float* Wx = (const float*)d_in[3];
  const float* Wh = (const float*)d_in[4];
  const float* b_lstm = (const float*)d_in[5];
  const float* Wenc = (const float*)d_in[6];
  const float* Wpred = (const float*)d_in[7];
  const float* b_joint = (const float*)d_in[8];
  const float* Wout = (const float*)d_in[9];
  const float* b_out = (const float*)d_in[10];
  float* out = (float*)d_out;
  (void)d_ws; (void)ws_size; (void)in_sizes; (void)n_in; (void)out_size;

  hipLaunchKernelGGL(k_lut, dim3(1290), dim3(256), 0, stream, embed, Wx, b_lstm);
  hipLaunchKernelGGL(k_encproj, dim3(160, 32), dim3(256), 0, stream, enc, Wenc, b_joint);
  hipLaunchKernelGGL(k_tr, dim3(4225), dim3(256), 0, stream, Wh, Wpred, Wout);
  hipLaunchKernelGGL(k_decode, dim3(NBLK), dim3(256), 0, stream, out, lens, b_out);
}